// Round 1
// baseline (207.976 us; speedup 1.0000x reference)
//
#include <hip/hip_runtime.h>
#include <cstdint>

#define GH 10
#define GW 10

// Round 6: occupancy push. rocprof showed latency-bound execution
// (VALUBusy 32.6%, Occupancy 25.8%, HBM 10% of peak): the 51.2 KB LDS
// tile capped residency at 3 blocks/CU (12 waves). Fix: stage through a
// 12.8 KB buffer in 4 chunks of 32 samples (chunk c's owners are exactly
// wave c), and move the one post-flood-fill gather (rn) from LDS to a
// 4-byte L2-resident global load. LDS/block 51.2 KB -> 12.9 KB; with
// __launch_bounds__(256,6) this doubles occupancy to 24 waves/CU.
// Per-sample arithmetic is unchanged (bit-identical loss).
__global__ __launch_bounds__(256, 6) void custom_loss_kernel(
    const float* __restrict__ result,
    const int* __restrict__ points,
    float* __restrict__ out,
    int B)
{
    __shared__ float lds[32 * 100];           // 12.8 KB chunk buffer
    __shared__ float wsum[4];
    const int tix = threadIdx.x;
    const int lane = tix & 63;
    const int wid = tix >> 6;

    const int s_local = tix >> 1;             // sample within block (0..127)
    const int h = tix & 1;                    // half: rows 5h..5h+4
    const int s = blockIdx.x * 128 + s_local;

    // points first: rs/re indices must be known during chunk residency
    int p0y = 0, p0x = 0, p1y = 0, p1x = 0;
    if (s < B) {
        const int4 p = ((const int4*)points)[s];
        p0y = p.x; p0x = p.y; p1y = p.z; p1x = p.w;
    }
    const int idx0 = p0y * GW + p0x;
    const int idx1 = p1y * GW + p1x;

    float vv[50];                             // own 5 rows, in registers
    float rs = 0.f, re = 0.f;

    // ---- staging: 4 chunks x 32 samples; coalesced float4, barriers ----
    {
        const size_t total4 = (size_t)B * 25;
        float4* lds4 = (float4*)lds;
        const float4* g4 = (const float4*)result;
#pragma unroll
        for (int c = 0; c < 4; ++c) {
            const size_t base4 = (size_t)blockIdx.x * 3200 + c * 800;
#pragma unroll
            for (int k = 0; k < 3; ++k) {     // 768 of 800 float4
                const int off = k * 256 + tix;
                if (base4 + off < total4) lds4[off] = g4[base4 + off];
            }
            const int off = 768 + tix;        // remaining 32 float4
            if (tix < 32 && base4 + off < total4) lds4[off] = g4[base4 + off];
            __syncthreads();                  // staging visible to wave c
            if (wid == c && s < B) {          // wave c copies its chunk
                const float* __restrict__ sp = lds + (lane >> 1) * 100;
                rs = sp[idx0];                // gathers while resident
                re = sp[idx1];
                const float2* rp2 = (const float2*)(sp + h * 50);
#pragma unroll
                for (int i = 0; i < 25; ++i) {
                    const float2 t = rp2[i];
                    vv[2 * i] = t.x; vv[2 * i + 1] = t.y;
                }
            }
            __syncthreads();                  // copy done before recycle
        }
    }

    float loss = 0.f;
    if (s < B) {
        const int dy0 = abs(p0y - p1y), dx0 = abs(p0x - p1x);
        const int base0 = dy0 + dx0;

        float adxf[10], inboxf[10];           // compile-time indexed -> regs
#pragma unroll
        for (int x = 0; x < 10; ++x) {
            const int a = abs(x - p0x) + abs(x - p1x) - dx0;
            adxf[x] = (float)a;
            inboxf[x] = (a == 0) ? 1.f : 0.f;
        }

        // ---- pass 1 over own rows ----
        float sum_h = 0.f, sc_h = 0.f, box_h = 0.f;
        uint64_t mword = 0;                   // own 50-bit mask, bit = i*10+x
#pragma unroll
        for (int i = 0; i < 5; ++i) {
            const int y = 5 * h + i;
            const float* v = vv + 10 * i;
            const float rowacc = ((v[0]+v[1])+(v[2]+v[3])) +
                                 ((v[4]+v[5])+(v[6]+v[7])) + (v[8]+v[9]);
            sum_h += rowacc;
            const int ay = abs(y - p0y) + abs(y - p1y) - dy0;
            sc_h = fmaf((float)ay, rowacc, sc_h);
            float boxrow = 0.f;
            uint32_t rm = 0u;
#pragma unroll
            for (int x = 0; x < 10; ++x) {
                sc_h = fmaf(adxf[x], v[x], sc_h);
                boxrow = fmaf(inboxf[x], v[x], boxrow);
                // jnp.round half-to-even: for v in [0,1), round==1 <=> v>0.5
                rm |= (v[x] > 0.5f) ? (1u << x) : 0u;
            }
            box_h += (ay == 0) ? boxrow : 0.f;
            mword |= (uint64_t)rm << (10 * i);
        }
        const float sum_all = sum_h + __shfl_xor(sum_h, 1);
        const float sc      = sc_h  + __shfl_xor(sc_h, 1);
        const float boxSum  = box_h + __shfl_xor(box_h, 1);
        const uint64_t mo = (uint64_t)__shfl_xor((unsigned long long)mword, 1);
        const uint64_t mlo = h ? mo : mword;
        const uint64_t mhi = h ? mword : mo;

        // ---- flood fill: full board per lane (no per-iter pair sync) ----
        const uint64_t M50 = (1ull << 50) - 1;
        const uint64_t C0  = 0x10040100401ull;        // col-0 bit of 5 rows
        const uint64_t NC0 = M50 & ~C0;
        const uint64_t NC9 = M50 & ~(C0 << 9);
        uint64_t clo = 0, chi = 0;
        if (idx0 < 50) clo = 1ull << idx0; else chi = 1ull << (idx0 - 50);
#pragma unroll 1
        for (int it = 0; it < GH + GW; ++it) {        // cap 20 = reference
            const uint64_t hlo = clo | ((clo << 1) & NC0) | ((clo >> 1) & NC9);
            const uint64_t hhi = chi | ((chi << 1) & NC0) | ((chi >> 1) & NC9);
            uint64_t nlo = (hlo | (hlo << 10) | (hlo >> 10) | ((hhi & 0x3FFull) << 40)) & mlo;
            uint64_t nhi = (hhi | (hhi << 10) | (hhi >> 10) | (hlo >> 40)) & mhi;
            nlo |= clo; nhi |= chi;
            if (nlo == clo && nhi == chi) break;      // exit only at fixpoint
            clo = nlo; chi = nhi;
        }
        const int K = __popcll(clo) + __popcll(chi);

        // ---- S_T over own cells (values still in registers) ----
        // in_cl[y][x] = cluster bit (x*10+y); y = 5h+i -> pre-shift by 5h
        const uint64_t wlo = clo >> (5 * h);
        const uint64_t whi = chi >> (5 * h);
        float st_h = 0.f;
#pragma unroll
        for (int i = 0; i < 5; ++i) {
            const float* v = vv + 10 * i;
#pragma unroll
            for (int x = 0; x < 10; ++x) {
                const uint64_t w = (x < 5) ? wlo : whi;    // compile-time sel
                const uint32_t bit = (uint32_t)((w >> ((x % 5) * 10 + i)) & 1ull);
                st_h = fmaf((float)bit, v[x], st_h);
            }
        }
        const float S_T = st_h + __shfl_xor(st_h, 1);

        // ---- argmin (own 5 rows, then pair merge; first-flat-index ties) ----
        int bestd = 1000, bidx = 0;
        const uint64_t cw = h ? chi : clo;
#pragma unroll
        for (int i = 0; i < 5; ++i) {
            const int y = 5 * h + i;
            const uint32_t rb = (uint32_t)((cw >> (10 * i)) & 0x3FFull);
            const uint32_t left  = rb & ((2u << p1x) - 1);
            const uint32_t right = rb >> p1x;
            const int dl = left  ? (p1x - (31 - __builtin_clz(left))) : 1000;
            const int dr = right ? __builtin_ctz(right) : 1000;
            int dx, xx;
            if (dl <= dr) { dx = dl; xx = p1x - dl; }      // tie -> smaller col
            else          { dx = dr; xx = p1x + dr; }
            const int d = abs(y - p1y) + dx;
            if (rb && d < bestd) { bestd = d; bidx = y * GW + xx; }
        }
        {   // pair merge; tie -> smaller flat index
            const int od = __shfl_xor(bestd, 1);
            const int oi = __shfl_xor(bidx, 1);
            if (od < bestd || (od == bestd && oi < bidx)) { bestd = od; bidx = oi; }
        }

        // ---- epilogue (replicated; only h==0 contributes) ----
        const bool better = bestd < base0;
        const int ny = better ? bidx / 10 : p0y;
        const int nx = better ? bidx % 10 : p0x;
        const int gap = min(base0, bestd);

        int by = ny, bx = nx, bg = gap;
        const int oy = p1y - ny, ox = p1x - nx;
        auto upd = [&](bool cond, int cy, int cx) {
            const int d = abs(cy - p1y) + abs(cx - p1x);
            if (cond && (d < bg)) { by = cy; bx = cx; bg = d; }
        };
        upd(ox < 0,                     ny,     nx - 1);
        upd((ox < 0) && (ny != 0),      ny - 1, nx - 1);
        upd((ox < 0) && (ny != GH - 1), ny + 1, nx - 1);
        upd(ox > 0,                     ny,     nx + 1);
        upd((ox > 0) && (ny != 0),      ny - 1, nx + 1);
        upd((ox > 0) && (ny != GH - 1), ny + 1, nx + 1);
        upd(oy < 0,                     ny - 1, nx);
        upd(oy > 0,                     ny + 1, nx);
        const int ncy = min(max(by, 0), GH - 1);
        const int ncx = min(max(bx, 0), GW - 1);
        // rn: 4-byte gather from global; block's window is L2/L3-resident.
        // (LDS board is gone by now -- that's what bought the occupancy.)
        const float rn = result[(size_t)s * 100 + ncy * GW + ncx];

        const float csf = (float)K;
        const float nboxf = (float)((dy0 + 1) * (dx0 + 1));
        const float loss_start = (2.f - (rs + re)) * 1000.f;
        const float lon = 5.f * csf + 15.f * sum_all - 20.f * S_T;
        const float single_cell = 0.5f * sc + 20.f * (nboxf - boxSum);
        const float cpen = 12.f * csf * S_T;
        const float gap_pen = (float)gap * 300.f * (1.f - rn);
        loss = loss_start + lon + single_cell + cpen + gap_pen;
        if (h != 0) loss = 0.f;                   // one contribution per sample
    }

    // ---- block reduction: wave shuffle -> LDS -> one atomic per block ----
#pragma unroll
    for (int off = 32; off > 0; off >>= 1)
        loss += __shfl_down(loss, off);
    if (lane == 0) wsum[wid] = loss;
    __syncthreads();
    if (tix == 0)
        atomicAdd(out, wsum[0] + wsum[1] + wsum[2] + wsum[3]);
}

extern "C" void kernel_launch(void* const* d_in, const int* in_sizes, int n_in,
                              void* d_out, int out_size, void* d_ws, size_t ws_size,
                              hipStream_t stream)
{
    const float* result = (const float*)d_in[0];
    const int* points   = (const int*)d_in[1];
    float* out = (float*)d_out;
    const int B = in_sizes[0] / 100;
    hipMemsetAsync(out, 0, sizeof(float), stream);   // harness poisons d_out
    const int block = 256;                            // 128 samples per block
    const int grid = (2 * B + block - 1) / block;
    custom_loss_kernel<<<grid, block, 0, stream>>>(result, points, out, B);
}

// Round 2
// 164.394 us; speedup vs baseline: 1.2651x; 1.2651x over previous
//
#include <hip/hip_runtime.h>
#include <cstdint>

#define GH 10
#define GW 10

// Round 7: no-LDS occupancy push. Round-6 post-mortem: __launch_bounds__(256,6)
// forced a spill of vv[50] to scratch (VGPR 68->40, WRITE_SIZE 64KB->99MB,
// 123.8us). Structural fact: any board-in-LDS scheme caps at ~12 waves/CU
// (400B/sample * 32 samples/wave = 12.8KB/wave vs 160KB LDS), while the
// registers-only board (~70 VGPR) allows 28 waves/CU. So: drop LDS staging
// entirely. Each lane loads its own 5 rows directly from global as 25x float2
// (stride 200B across lanes; every byte consumed, window L1/L2-resident for
// the rs/re/rn gathers). launch_bounds(256,4) caps VGPR at 128 -> no spill.
// Per-sample arithmetic identical to round 0 (bit-identical loss).
__global__ __launch_bounds__(256, 4) void custom_loss_kernel(
    const float* __restrict__ result,
    const int* __restrict__ points,
    float* __restrict__ out,
    int B)
{
    __shared__ float wsum[4];
    const int tix = threadIdx.x;
    const int lane = tix & 63;
    const int wid = tix >> 6;

    const int s_local = tix >> 1;             // sample within block (0..127)
    const int h = tix & 1;                    // half: rows 5h..5h+4
    const int s = blockIdx.x * 128 + s_local;

    float loss = 0.f;
    if (s < B) {
        const int4 p = ((const int4*)points)[s];
        const int p0y = p.x, p0x = p.y, p1y = p.z, p1x = p.w;
        const int dy0 = abs(p0y - p1y), dx0 = abs(p0x - p1x);
        const int base0 = dy0 + dx0;
        const int idx0 = p0y * GW + p0x;
        const int idx1 = p1y * GW + p1x;

        // ---- own 5 rows (50 floats) straight from global into registers ----
        const float* __restrict__ sp = result + (size_t)s * 100;
        const float2* __restrict__ rp2 = (const float2*)(sp + h * 50);
        float vv[50];
#pragma unroll
        for (int i = 0; i < 25; ++i) {
            const float2 t = rp2[i];
            vv[2 * i] = t.x; vv[2 * i + 1] = t.y;
        }
        const float rs = sp[idx0];            // L1-hot: lines just fetched
        const float re = sp[idx1];

        float adxf[10], inboxf[10];           // compile-time indexed -> regs
#pragma unroll
        for (int x = 0; x < 10; ++x) {
            const int a = abs(x - p0x) + abs(x - p1x) - dx0;
            adxf[x] = (float)a;
            inboxf[x] = (a == 0) ? 1.f : 0.f;
        }

        // ---- pass 1 over own rows ----
        float sum_h = 0.f, sc_h = 0.f, box_h = 0.f;
        uint64_t mword = 0;                   // own 50-bit mask, bit = i*10+x
#pragma unroll
        for (int i = 0; i < 5; ++i) {
            const int y = 5 * h + i;
            const float* v = vv + 10 * i;
            const float rowacc = ((v[0]+v[1])+(v[2]+v[3])) +
                                 ((v[4]+v[5])+(v[6]+v[7])) + (v[8]+v[9]);
            sum_h += rowacc;
            const int ay = abs(y - p0y) + abs(y - p1y) - dy0;
            sc_h = fmaf((float)ay, rowacc, sc_h);
            float boxrow = 0.f;
            uint32_t rm = 0u;
#pragma unroll
            for (int x = 0; x < 10; ++x) {
                sc_h = fmaf(adxf[x], v[x], sc_h);
                boxrow = fmaf(inboxf[x], v[x], boxrow);
                // jnp.round half-to-even: for v in [0,1), round==1 <=> v>0.5
                rm |= (v[x] > 0.5f) ? (1u << x) : 0u;
            }
            box_h += (ay == 0) ? boxrow : 0.f;
            mword |= (uint64_t)rm << (10 * i);
        }
        const float sum_all = sum_h + __shfl_xor(sum_h, 1);
        const float sc      = sc_h  + __shfl_xor(sc_h, 1);
        const float boxSum  = box_h + __shfl_xor(box_h, 1);
        const uint64_t mo = (uint64_t)__shfl_xor((unsigned long long)mword, 1);
        const uint64_t mlo = h ? mo : mword;
        const uint64_t mhi = h ? mword : mo;

        // ---- flood fill: full board per lane (no per-iter pair sync) ----
        const uint64_t M50 = (1ull << 50) - 1;
        const uint64_t C0  = 0x10040100401ull;        // col-0 bit of 5 rows
        const uint64_t NC0 = M50 & ~C0;
        const uint64_t NC9 = M50 & ~(C0 << 9);
        uint64_t clo = 0, chi = 0;
        if (idx0 < 50) clo = 1ull << idx0; else chi = 1ull << (idx0 - 50);
#pragma unroll 1
        for (int it = 0; it < GH + GW; ++it) {        // cap 20 = reference
            const uint64_t hlo = clo | ((clo << 1) & NC0) | ((clo >> 1) & NC9);
            const uint64_t hhi = chi | ((chi << 1) & NC0) | ((chi >> 1) & NC9);
            uint64_t nlo = (hlo | (hlo << 10) | (hlo >> 10) | ((hhi & 0x3FFull) << 40)) & mlo;
            uint64_t nhi = (hhi | (hhi << 10) | (hhi >> 10) | (hlo >> 40)) & mhi;
            nlo |= clo; nhi |= chi;
            if (nlo == clo && nhi == chi) break;      // exit only at fixpoint
            clo = nlo; chi = nhi;
        }
        const int K = __popcll(clo) + __popcll(chi);

        // ---- S_T over own cells (values still in registers) ----
        // in_cl[y][x] = cluster bit (x*10+y); y = 5h+i -> pre-shift by 5h
        const uint64_t wlo = clo >> (5 * h);
        const uint64_t whi = chi >> (5 * h);
        float st_h = 0.f;
#pragma unroll
        for (int i = 0; i < 5; ++i) {
            const float* v = vv + 10 * i;
#pragma unroll
            for (int x = 0; x < 10; ++x) {
                const uint64_t w = (x < 5) ? wlo : whi;    // compile-time sel
                const uint32_t bit = (uint32_t)((w >> ((x % 5) * 10 + i)) & 1ull);
                st_h = fmaf((float)bit, v[x], st_h);
            }
        }
        const float S_T = st_h + __shfl_xor(st_h, 1);

        // ---- argmin (own 5 rows, then pair merge; first-flat-index ties) ----
        int bestd = 1000, bidx = 0;
        const uint64_t cw = h ? chi : clo;
#pragma unroll
        for (int i = 0; i < 5; ++i) {
            const int y = 5 * h + i;
            const uint32_t rb = (uint32_t)((cw >> (10 * i)) & 0x3FFull);
            const uint32_t left  = rb & ((2u << p1x) - 1);
            const uint32_t right = rb >> p1x;
            const int dl = left  ? (p1x - (31 - __builtin_clz(left))) : 1000;
            const int dr = right ? __builtin_ctz(right) : 1000;
            int dx, xx;
            if (dl <= dr) { dx = dl; xx = p1x - dl; }      // tie -> smaller col
            else          { dx = dr; xx = p1x + dr; }
            const int d = abs(y - p1y) + dx;
            if (rb && d < bestd) { bestd = d; bidx = y * GW + xx; }
        }
        {   // pair merge; tie -> smaller flat index
            const int od = __shfl_xor(bestd, 1);
            const int oi = __shfl_xor(bidx, 1);
            if (od < bestd || (od == bestd && oi < bidx)) { bestd = od; bidx = oi; }
        }

        // ---- epilogue (replicated; only h==0 contributes) ----
        const bool better = bestd < base0;
        const int ny = better ? bidx / 10 : p0y;
        const int nx = better ? bidx % 10 : p0x;
        const int gap = min(base0, bestd);

        int by = ny, bx = nx, bg = gap;
        const int oy = p1y - ny, ox = p1x - nx;
        auto upd = [&](bool cond, int cy, int cx) {
            const int d = abs(cy - p1y) + abs(cx - p1x);
            if (cond && (d < bg)) { by = cy; bx = cx; bg = d; }
        };
        upd(ox < 0,                     ny,     nx - 1);
        upd((ox < 0) && (ny != 0),      ny - 1, nx - 1);
        upd((ox < 0) && (ny != GH - 1), ny + 1, nx - 1);
        upd(ox > 0,                     ny,     nx + 1);
        upd((ox > 0) && (ny != 0),      ny - 1, nx + 1);
        upd((ox > 0) && (ny != GH - 1), ny + 1, nx + 1);
        upd(oy < 0,                     ny - 1, nx);
        upd(oy > 0,                     ny + 1, nx);
        const int ncy = min(max(by, 0), GH - 1);
        const int ncx = min(max(bx, 0), GW - 1);
        const float rn = sp[ncy * GW + ncx];  // L1/L2-hot gather

        const float csf = (float)K;
        const float nboxf = (float)((dy0 + 1) * (dx0 + 1));
        const float loss_start = (2.f - (rs + re)) * 1000.f;
        const float lon = 5.f * csf + 15.f * sum_all - 20.f * S_T;
        const float single_cell = 0.5f * sc + 20.f * (nboxf - boxSum);
        const float cpen = 12.f * csf * S_T;
        const float gap_pen = (float)gap * 300.f * (1.f - rn);
        loss = loss_start + lon + single_cell + cpen + gap_pen;
        if (h != 0) loss = 0.f;                   // one contribution per sample
    }

    // ---- block reduction: wave shuffle -> LDS -> one atomic per block ----
#pragma unroll
    for (int off = 32; off > 0; off >>= 1)
        loss += __shfl_down(loss, off);
    if (lane == 0) wsum[wid] = loss;
    __syncthreads();
    if (tix == 0)
        atomicAdd(out, wsum[0] + wsum[1] + wsum[2] + wsum[3]);
}

extern "C" void kernel_launch(void* const* d_in, const int* in_sizes, int n_in,
                              void* d_out, int out_size, void* d_ws, size_t ws_size,
                              hipStream_t stream)
{
    const float* result = (const float*)d_in[0];
    const int* points   = (const int*)d_in[1];
    float* out = (float*)d_out;
    const int B = in_sizes[0] / 100;
    hipMemsetAsync(out, 0, sizeof(float), stream);   // harness poisons d_out
    const int block = 256;                            // 128 samples per block
    const int grid = (2 * B + block - 1) / block;
    custom_loss_kernel<<<grid, block, 0, stream>>>(result, points, out, B);
}